// Round 1
// 733.696 us; speedup vs baseline: 1.0842x; 1.0842x over previous
//
#include <hip/hip_runtime.h>
#include <hip/hip_bf16.h>

typedef __attribute__((ext_vector_type(8))) short short8;
typedef __attribute__((ext_vector_type(4))) float f32x4;

#define NSAMP 50
#define MTOT 204800   // B*S*NS
#define BS_TOT 4096   // B*S

__device__ __forceinline__ unsigned short f2bf(float f) {
  unsigned int u = __builtin_bit_cast(unsigned int, f);
  u += 0x7fffu + ((u >> 16) & 1u);   // RNE
  return (unsigned short)(u >> 16);
}

// pack trunc(a),trunc(b) -> dword in ONE v_perm_b32 (bytes a2,a3,b2,b3)
__device__ __forceinline__ unsigned int pk_bf_trunc(float a, float b) {
  return __builtin_amdgcn_perm(__builtin_bit_cast(unsigned int, b),
                               __builtin_bit_cast(unsigned int, a), 0x07060302u);
}

__device__ __forceinline__ float softplusf(float x) {
  return fmaxf(x, 0.f) + log1pf(__expf(-fabsf(x)));
}

// ---------------- K0: w_noise -> bf16 --------------------------------------
__global__ __launch_bounds__(256) void k0_prep(const float* __restrict__ w_noise,
                                               unsigned short* __restrict__ wn_bf) {
  int r = blockIdx.x;            // 512 rows
  int t = threadIdx.x;
#pragma unroll
  for (int q = 0; q < 2; ++q) {
    int col = t + 256 * q;
    wn_bf[r * 512 + col] = f2bf(w_noise[r * 512 + col]);
  }
}

// ---------------- K1: embeddings + per-event dot products ------------------
__global__ __launch_bounds__(256) void k1_embed(const int* __restrict__ etype,
    const float* __restrict__ etime, const float* __restrict__ wt,
    const float* __restrict__ table, const float* __restrict__ w_sigma,
    const float* __restrict__ w_gate, float* __restrict__ hv,
    float* __restrict__ ab) {
  int bs = blockIdx.x;           // 4096
  int d = threadIdx.x;           // 256
  int s = bs & 1023;
  int ty = etype[bs];
  float te = table[ty * 256 + d];
  float t = etime[bs];
  int k = d & 127;
  float div_term = __expf((float)(2 * k) * (-9.210340371976184f / 256.f));
  float arg = (float)s * div_term + t * wt[k];
  float pe = (d < 128) ? sinf(arg) : cosf(arg);
  hv[(size_t)bs * 512 + d] = pe;
  hv[(size_t)bs * 512 + 256 + d] = te;
  float p0 = te * w_sigma[d];
  float p1 = te * w_sigma[256 + d];
  float p2 = te * w_gate[d];
  float p3 = te * w_gate[256 + d];
#pragma unroll
  for (int m = 1; m < 64; m <<= 1) {
    p0 += __shfl_xor(p0, m, 64);
    p1 += __shfl_xor(p1, m, 64);
    p2 += __shfl_xor(p2, m, 64);
    p3 += __shfl_xor(p3, m, 64);
  }
  __shared__ float red[4][4];
  if ((d & 63) == 0) {
    red[d >> 6][0] = p0; red[d >> 6][1] = p1;
    red[d >> 6][2] = p2; red[d >> 6][3] = p3;
  }
  __syncthreads();
  if (d < 4) ab[d * BS_TOT + bs] = red[0][d] + red[1][d] + red[2][d] + red[3][d];
}

// ---------------- K1t: hv[bs][512] -> hvT_bf[b][h][s] (bf16 transpose) -----
__global__ __launch_bounds__(256) void k1t_transpose(const float* __restrict__ hv,
                                                     unsigned short* __restrict__ hvT) {
  __shared__ float T[64][65];
  int bid = blockIdx.x;          // 4 * 16 * 8 = 512
  int b = bid >> 7;
  int st = (bid & 127) >> 3;
  int ht = bid & 7;
  int s0 = st * 64, h0 = ht * 64;
  int t = threadIdx.x;
#pragma unroll
  for (int q = 0; q < 16; ++q) {
    int idx = t + 256 * q;
    int r = idx >> 6, c = idx & 63;
    T[c][r] = hv[((size_t)(b * 1024 + s0 + r)) * 512 + h0 + c];
  }
  __syncthreads();
  int sq = t & 15;
#pragma unroll
  for (int q = 0; q < 4; ++q) {
    int hh = (t >> 4) + 16 * q;
    ushort4 u;
    u.x = f2bf(T[hh][sq * 4 + 0]);
    u.y = f2bf(T[hh][sq * 4 + 1]);
    u.z = f2bf(T[hh][sq * 4 + 2]);
    u.w = f2bf(T[hh][sq * 4 + 3]);
    *(ushort4*)(hvT + ((size_t)b << 19) + ((size_t)(h0 + hh) << 10) + s0 + sq * 4) = u;
  }
}

// ---------------- K2a: scores -> bf16 [b][i][j], zero for j>=i -------------
__global__ __launch_bounds__(256) void k2a_scores(const float* __restrict__ etime,
    const float* __restrict__ ab, unsigned short* __restrict__ S) {
  __shared__ float ti[8], bsi[8], bgi[8];
  int bid = blockIdx.x;          // 4 * 128 = 512
  int b = bid >> 7;
  int i0 = (bid & 127) * 8;
  int t = threadIdx.x;
  const float* et_b = etime + b * 1024;
  const float* as_b = ab + 0 * BS_TOT + b * 1024;
  const float* bs_b = ab + 1 * BS_TOT + b * 1024;
  const float* ag_b = ab + 2 * BS_TOT + b * 1024;
  const float* bg_b = ab + 3 * BS_TOT + b * 1024;
  if (t < 8) {
    ti[t] = et_b[i0 + t];
    bsi[t] = bs_b[i0 + t];
    bgi[t] = bg_b[i0 + t];
  }
  __syncthreads();
  unsigned short* Sb = S + ((size_t)b << 20);
  for (int j0 = 0; j0 < 1024; j0 += 256) {
    int j = j0 + t;
    float as_j = as_b[j], ag_j = ag_b[j], tj = et_b[j];
#pragma unroll
    for (int il = 0; il < 8; ++il) {
      int i = i0 + il;
      float sc = 0.f;
      if (j < i) {
        float sp = softplusf(as_j + bsi[il]);
        float g = 1.f / (1.f + __expf(-(ag_j + bgi[il])));
        sc = g * __expf(-sp * fabsf(tj - ti[il]));
      }
      Sb[((size_t)i << 10) + j] = f2bf(sc);
    }
  }
}

// ---------------- K2b: hidden = S @ hv  (bf16 MFMA, causal k-stop) ---------
// m-tile 64 -> grid 256 (full machine). [.][32] LDS = 64B stride, no conflicts.
__global__ __launch_bounds__(256) void k2b_agg(const unsigned short* __restrict__ S,
    const unsigned short* __restrict__ hvT, float* __restrict__ hidden) {
  __shared__ unsigned short As[64][32];
  __shared__ unsigned short Bs[128][32];
  int bid = blockIdx.x;          // 4b * 16mt * 4nt = 256
  int b = bid >> 6;
  int mt = (bid >> 2) & 15;
  int nt = bid & 3;
  int i0 = mt * 64, n0 = nt * 128;
  int kmax = i0 + 64;
  int tid = threadIdx.x;
  int lane = tid & 63, wv = tid >> 6;
  int wm = wv >> 1, wn = wv & 1;
  int quad = lane >> 4, lcol = lane & 15;
  const unsigned short* Sb = S + ((size_t)b << 20);
  const unsigned short* Hb = hvT + ((size_t)b << 19);
  f32x4 acc[2][4] = {};
  for (int kt = 0; kt < kmax; kt += 32) {
    __syncthreads();
    {
      int row = tid >> 2, kq = (tid & 3) << 3;
      *(uint4*)&As[row][kq] = *(const uint4*)(Sb + (((size_t)(i0 + row)) << 10) + kt + kq);
    }
#pragma unroll
    for (int q = 0; q < 2; ++q) {
      int c = tid + 256 * q;
      int row = c >> 2, kq = (c & 3) << 3;
      *(uint4*)&Bs[row][kq] = *(const uint4*)(Hb + (((size_t)(n0 + row)) << 10) + kt + kq);
    }
    __syncthreads();
    short8 af[2], bfr[4];
#pragma unroll
    for (int i = 0; i < 2; ++i)
      af[i] = *(const short8*)&As[wm * 32 + i * 16 + lcol][quad * 8];
#pragma unroll
    for (int j = 0; j < 4; ++j)
      bfr[j] = *(const short8*)&Bs[wn * 64 + j * 16 + lcol][quad * 8];
#pragma unroll
    for (int i = 0; i < 2; ++i)
#pragma unroll
      for (int j = 0; j < 4; ++j)
        acc[i][j] = __builtin_amdgcn_mfma_f32_16x16x32_bf16(af[i], bfr[j],
                                                            acc[i][j], 0, 0, 0);
  }
#pragma unroll
  for (int i = 0; i < 2; ++i) {
    int rowb = i0 + wm * 32 + i * 16 + quad * 4;
#pragma unroll
    for (int j = 0; j < 4; ++j) {
      int col = n0 + wn * 64 + j * 16 + lcol;
#pragma unroll
      for (int r = 0; r < 4; ++r)
        hidden[((size_t)(b * 1024 + rowb + r)) * 512 + col] = acc[i][j][r];
    }
  }
}

// ---------------- K2c: LayerNorm + mark softmax + hidden_n -> bf16 ---------
__global__ __launch_bounds__(256) void k2c_ln(const float* __restrict__ hidden,
    const float* __restrict__ ln_g, const float* __restrict__ ln_b,
    const float* __restrict__ w_pred, unsigned short* __restrict__ hn,
    float* __restrict__ out) {
  int row = blockIdx.x * 4 + (threadIdx.x >> 6);   // 4096 rows
  int l = threadIdx.x & 63;
  const float* hr = hidden + (size_t)row * 512 + 8 * l;
  float4 x0 = *(const float4*)hr;
  float4 x1 = *(const float4*)(hr + 4);
  float sm = x0.x + x0.y + x0.z + x0.w + x1.x + x1.y + x1.z + x1.w;
#pragma unroll
  for (int m = 1; m < 64; m <<= 1) sm += __shfl_xor(sm, m, 64);
  float mu = sm * (1.f / 512.f);
  float d[8] = {x0.x - mu, x0.y - mu, x0.z - mu, x0.w - mu,
                x1.x - mu, x1.y - mu, x1.z - mu, x1.w - mu};
  float vs = 0.f;
#pragma unroll
  for (int e = 0; e < 8; ++e) vs += d[e] * d[e];
#pragma unroll
  for (int m = 1; m < 64; m <<= 1) vs += __shfl_xor(vs, m, 64);
  float rs = rsqrtf(vs * (1.f / 512.f) + 1e-6f);
  float4 g0 = *(const float4*)(ln_g + 8 * l);
  float4 g1 = *(const float4*)(ln_g + 8 * l + 4);
  float4 b0 = *(const float4*)(ln_b + 8 * l);
  float4 b1 = *(const float4*)(ln_b + 8 * l + 4);
  float hnv[8];
  hnv[0] = d[0] * rs * g0.x + b0.x; hnv[1] = d[1] * rs * g0.y + b0.y;
  hnv[2] = d[2] * rs * g0.z + b0.z; hnv[3] = d[3] * rs * g0.w + b0.w;
  hnv[4] = d[4] * rs * g1.x + b1.x; hnv[5] = d[5] * rs * g1.y + b1.y;
  hnv[6] = d[6] * rs * g1.z + b1.z; hnv[7] = d[7] * rs * g1.w + b1.w;
  ushort4 u0, u1;
  u0.x = f2bf(hnv[0]); u0.y = f2bf(hnv[1]); u0.z = f2bf(hnv[2]); u0.w = f2bf(hnv[3]);
  u1.x = f2bf(hnv[4]); u1.y = f2bf(hnv[5]); u1.z = f2bf(hnv[6]); u1.w = f2bf(hnv[7]);
  *(ushort4*)(hn + (size_t)row * 512 + 8 * l) = u0;
  *(ushort4*)(hn + (size_t)row * 512 + 8 * l + 4) = u1;
  // mark logits
  float lg[20];
#pragma unroll
  for (int p = 0; p < 20; ++p) {
    const float* wp = w_pred + p * 512 + 8 * l;
    float4 w0 = *(const float4*)wp;
    float4 w1 = *(const float4*)(wp + 4);
    float v = hnv[0] * w0.x + hnv[1] * w0.y + hnv[2] * w0.z + hnv[3] * w0.w +
              hnv[4] * w1.x + hnv[5] * w1.y + hnv[6] * w1.z + hnv[7] * w1.w;
#pragma unroll
    for (int m = 1; m < 64; m <<= 1) v += __shfl_xor(v, m, 64);
    lg[p] = v;
  }
  if (l == 0) {
    float mx = -1e30f;
#pragma unroll
    for (int p = 0; p < 20; ++p) mx = fmaxf(mx, lg[p]);
    float e[20], sum = 0.f;
#pragma unroll
    for (int p = 0; p < 20; ++p) { e[p] = __expf(lg[p] - mx); sum += e[p]; }
    float inv = 1.f / sum;
    float* o = out + 4096 + (size_t)row * 20;
#pragma unroll
    for (int p = 0; p < 20; ++p) o[p] = e[p] * inv;
  }
}

// ---------------- K2d: cbuf = hidden_n @ w_in^T (bf16 MFMA, m-tile 64) -----
__global__ __launch_bounds__(256) void k2d_cbuf(const unsigned short* __restrict__ hn,
    const float* __restrict__ w_in, float* __restrict__ cbuf) {
  __shared__ unsigned short As[64][32];
  __shared__ unsigned short Bs[128][32];
  int bid = blockIdx.x;          // 64mt * 4nt = 256
  int mt = bid >> 2, nt = bid & 3;
  int m0 = mt * 64, n0 = nt * 128;
  int tid = threadIdx.x;
  int lane = tid & 63, wv = tid >> 6;
  int wm = wv >> 1, wn = wv & 1;
  int quad = lane >> 4, lcol = lane & 15;
  f32x4 acc[2][4] = {};
  for (int kt = 0; kt < 512; kt += 32) {
    __syncthreads();
    {
      int row = tid >> 2, kq = (tid & 3) << 3;
      *(uint4*)&As[row][kq] = *(const uint4*)(hn + (((size_t)(m0 + row)) << 9) + kt + kq);
    }
#pragma unroll
    for (int q = 0; q < 4; ++q) {
      int c = tid + 256 * q;
      int row = c >> 3, kq = (c & 7) << 2;
      float4 f = *(const float4*)(w_in + ((size_t)(n0 + row) << 9) + kt + kq);
      unsigned int p0 = pk_bf_trunc(f.x, f.y);
      unsigned int p1 = pk_bf_trunc(f.z, f.w);
      *(uint2*)&Bs[row][kq] = make_uint2(p0, p1);
    }
    __syncthreads();
    short8 af[2], bfr[4];
#pragma unroll
    for (int i = 0; i < 2; ++i)
      af[i] = *(const short8*)&As[wm * 32 + i * 16 + lcol][quad * 8];
#pragma unroll
    for (int j = 0; j < 4; ++j)
      bfr[j] = *(const short8*)&Bs[wn * 64 + j * 16 + lcol][quad * 8];
#pragma unroll
    for (int i = 0; i < 2; ++i)
#pragma unroll
      for (int j = 0; j < 4; ++j)
        acc[i][j] = __builtin_amdgcn_mfma_f32_16x16x32_bf16(af[i], bfr[j],
                                                            acc[i][j], 0, 0, 0);
  }
#pragma unroll
  for (int i = 0; i < 2; ++i) {
    int rowb = m0 + wm * 32 + i * 16 + quad * 4;
#pragma unroll
    for (int j = 0; j < 4; ++j) {
      int col = n0 + wn * 64 + j * 16 + lcol;
#pragma unroll
      for (int r = 0; r < 4; ++r)
        cbuf[((size_t)(rowb + r)) * 512 + col] = acc[i][j][r];
    }
  }
}

// ---------------- K4: bf16 MFMA GEMM h=relu(noise@w_noise^T + c) -----------
// Pipelined rewrite: double-buffered LDS (2x16KB A + 2x16KB B = 64KB exactly),
// issue-early/write-late reg staging (T14) so each K-step's global loads hide
// under the previous step's MFMA phase; ONE barrier per K-step; setprio around
// the MFMA cluster (T5). XOR-swizzled LDS (conflict-free, verified 0 in PMC);
// XCD-aligned sibling swizzle kept. v_s epilogue buffer aliases As[0].
__global__ __launch_bounds__(256, 2) void k4_gemm(const float* __restrict__ noise,
    const unsigned short* __restrict__ wn_bf, const float* __restrict__ cbuf,
    const float* __restrict__ w_time, float* __restrict__ v_part) {
  __shared__ unsigned short As[2][128][64];
  __shared__ unsigned short Bs[2][128][64];
  int tid = threadIdx.x;
  // blockIdx = g*32 + r : mt = g*8 + (r&7), nt = r>>3  -> siblings differ by 8
  int gg = blockIdx.x >> 5, rr = blockIdx.x & 31;
  int nt = rr >> 3;
  int mt = (gg << 3) + (rr & 7);
  size_t m0 = (size_t)mt * 128;
  int n0 = nt * 128;
  int lane = tid & 63, wv = tid >> 6;
  int wm = wv >> 1, wn = wv & 1;
  int quad = lane >> 4, lcol = lane & 15;
  int m7 = lcol & 7;              // per-lane xor mask for fragment reads

  // A staging geometry: per q (0..7): row = (tid>>4) + 16q, cols akq..akq+3
  int arow = tid >> 4;
  int akq = (tid & 15) << 2;                               // float col in [0,64)
  int apc = (((akq >> 3) ^ (arow & 7)) << 3) | (akq & 7);  // q-invariant swizzle
  const float* aptr = noise + ((m0 + arow) << 9) + akq;
  // B staging geometry: per q (0..3): row = (tid>>3) + 32q, cols (tid&7)*8..+7
  int brow = tid >> 3;
  int bpc = ((tid & 7) ^ (brow & 7)) << 3;                 // q-invariant swizzle
  const unsigned short* bptr = wn_bf + (((size_t)(n0 + brow)) << 9) + ((tid & 7) << 3);

  f32x4 acc[4][4] = {};
  float4 rA[8];
  uint4 rB[4];

#define A_ISSUE(KT) { _Pragma("unroll") for (int q = 0; q < 8; ++q) \
    rA[q] = *(const float4*)(aptr + (q << 13) + (KT) * 64); }
#define B_ISSUE(KT) { _Pragma("unroll") for (int q = 0; q < 4; ++q) \
    rB[q] = *(const uint4*)(bptr + (q << 14) + (KT) * 64); }
#define AB_WRITE(BUF) { _Pragma("unroll") for (int q = 0; q < 8; ++q) { \
      unsigned int p0 = pk_bf_trunc(rA[q].x, rA[q].y); \
      unsigned int p1 = pk_bf_trunc(rA[q].z, rA[q].w); \
      *(uint2*)&As[BUF][arow + 16 * q][apc] = make_uint2(p0, p1); } \
    _Pragma("unroll") for (int q = 0; q < 4; ++q) \
      *(uint4*)&Bs[BUF][brow + 32 * q][bpc] = rB[q]; }
#define COMPUTE(BUF) { _Pragma("unroll") for (int kk = 0; kk < 64; kk += 32) { \
      int pcf = ((quad + (kk >> 3)) ^ m7) << 3; \
      short8 af[4], bfr[4]; \
      _Pragma("unroll") for (int i = 0; i < 4; ++i) \
        af[i] = *(const short8*)&As[BUF][wm * 64 + i * 16 + lcol][pcf]; \
      _Pragma("unroll") for (int j = 0; j < 4; ++j) \
        bfr[j] = *(const short8*)&Bs[BUF][wn * 64 + j * 16 + lcol][pcf]; \
      __builtin_amdgcn_s_setprio(1); \
      _Pragma("unroll") for (int i = 0; i < 4; ++i) \
        _Pragma("unroll") for (int j = 0; j < 4; ++j) \
          acc[i][j] = __builtin_amdgcn_mfma_f32_16x16x32_bf16(af[i], bfr[j], \
                                                              acc[i][j], 0, 0, 0); \
      __builtin_amdgcn_s_setprio(0); } }

  // prologue: stage K-tile 0 into buffer 0
  A_ISSUE(0); B_ISSUE(0);
  AB_WRITE(0);                    // compiler inserts vmcnt wait before first use
  __syncthreads();

#pragma unroll
  for (int kt = 0; kt < 8; ++kt) {
    if (kt < 7) { A_ISSUE(kt + 1); B_ISSUE(kt + 1); }   // fire-and-forget
    __builtin_amdgcn_sched_barrier(0);                  // don't sink loads below MFMA
    if ((kt & 1) == 0) {
      COMPUTE(0);
      if (kt < 7) AB_WRITE(1);    // vmcnt wait here: loads had whole MFMA phase
    } else {
      COMPUTE(1);
      if (kt < 7) AB_WRITE(0);
    }
    __syncthreads();              // one barrier per K-step
  }

#undef A_ISSUE
#undef B_ISSUE
#undef AB_WRITE
#undef COMPUTE

  // epilogue: v_s aliases As[0] (all LDS reads of it completed at last barrier)
  float* v_s = (float*)&As[0][0][0];
  if (tid < 128) v_s[tid] = 0.f;
  __syncthreads();
  float rowsum[4][4];
#pragma unroll
  for (int i = 0; i < 4; ++i)
#pragma unroll
    for (int r = 0; r < 4; ++r) rowsum[i][r] = 0.f;
#pragma unroll
  for (int i = 0; i < 4; ++i) {
    int rowb = wm * 64 + i * 16 + quad * 4;
#pragma unroll
    for (int j = 0; j < 4; ++j) {
      int col = n0 + wn * 64 + j * 16 + lcol;
      float wtv = w_time[col];
#pragma unroll
      for (int r = 0; r < 4; ++r) {
        int grow = (int)m0 + rowb + r;
        int bs = grow / NSAMP;
        float hval = acc[i][j][r] + cbuf[((size_t)bs << 9) + col];
        rowsum[i][r] += fmaxf(hval, 0.f) * wtv;
      }
    }
  }
#pragma unroll
  for (int i = 0; i < 4; ++i)
#pragma unroll
    for (int r = 0; r < 4; ++r) {
      float v = rowsum[i][r];
      v += __shfl_xor(v, 1, 64);
      v += __shfl_xor(v, 2, 64);
      v += __shfl_xor(v, 4, 64);
      v += __shfl_xor(v, 8, 64);
      if (lcol == 0) atomicAdd(&v_s[wm * 64 + i * 16 + quad * 4 + r], v);
    }
  __syncthreads();
  if (tid < 128) v_part[(size_t)nt * MTOT + m0 + tid] = v_s[tid];
}

// ---------------- K5: pred_time = mean_n softplus(sum of partials) ---------
__global__ __launch_bounds__(64) void k5_pred(const float* __restrict__ v_part,
                                              float* __restrict__ out) {
  int bs = blockIdx.x;
  int t = threadIdx.x;
  float sp = 0.f;
  if (t < NSAMP) {
    size_t idx = (size_t)bs * NSAMP + t;
    float v = v_part[idx] + v_part[(size_t)MTOT + idx] +
              v_part[2 * (size_t)MTOT + idx] + v_part[3 * (size_t)MTOT + idx];
    sp = softplusf(v);
  }
#pragma unroll
  for (int m = 1; m < 64; m <<= 1) sp += __shfl_xor(sp, m, 64);
  if (t == 0) out[bs] = sp * (1.f / NSAMP);
}

extern "C" void kernel_launch(void* const* d_in, const int* in_sizes, int n_in,
                              void* d_out, int out_size, void* d_ws, size_t ws_size,
                              hipStream_t stream) {
  const int* etype    = (const int*)d_in[0];
  const float* etime  = (const float*)d_in[1];
  const float* noise  = (const float*)d_in[2];
  const float* wt     = (const float*)d_in[3];
  const float* table  = (const float*)d_in[4];
  const float* w_sigma= (const float*)d_in[5];
  const float* w_gate = (const float*)d_in[6];
  const float* ln_g   = (const float*)d_in[7];
  const float* ln_b   = (const float*)d_in[8];
  const float* w_pred = (const float*)d_in[9];
  const float* w_in   = (const float*)d_in[10];
  const float* w_noise= (const float*)d_in[11];
  const float* w_time = (const float*)d_in[12];
  float* out = (float*)d_out;
  char* ws = (char*)d_ws;
  // workspace overlays by lifetime (21.56 MB total):
  // R0 (8MB):  hv (k1-k1t) -> hidden (k2b-k2c) -> cbuf (k2d-k4)
  // R1 (8MB):  S_bf (k2a-k2b) -> v_part (k4-k5)
  // R2 (4MB):  hvT_bf (k1t-k2b) -> hidden_n (k2c-k2d)
  // R3: wn_bf 512KB ; R4: ab 64KB
  float* hv             = (float*)(ws);
  float* hidden         = (float*)(ws);
  float* cbuf           = (float*)(ws);
  unsigned short* S_bf  = (unsigned short*)(ws + 8388608);
  float* v_part         = (float*)(ws + 8388608);
  unsigned short* hvT   = (unsigned short*)(ws + 16777216);
  unsigned short* hn    = (unsigned short*)(ws + 16777216);
  unsigned short* wn_bf = (unsigned short*)(ws + 20971520);
  float* ab             = (float*)(ws + 21495808);

  hipLaunchKernelGGL(k0_prep, dim3(512), dim3(256), 0, stream, w_noise, wn_bf);
  hipLaunchKernelGGL(k1_embed, dim3(4096), dim3(256), 0, stream,
                     etype, etime, wt, table, w_sigma, w_gate, hv, ab);
  hipLaunchKernelGGL(k1t_transpose, dim3(512), dim3(256), 0, stream, hv, hvT);
  hipLaunchKernelGGL(k2a_scores, dim3(512), dim3(256), 0, stream, etime, ab, S_bf);
  hipLaunchKernelGGL(k2b_agg, dim3(256), dim3(256), 0, stream, S_bf, hvT, hidden);
  hipLaunchKernelGGL(k2c_ln, dim3(1024), dim3(256), 0, stream,
                     hidden, ln_g, ln_b, w_pred, hn, out);
  hipLaunchKernelGGL(k2d_cbuf, dim3(256), dim3(256), 0, stream, hn, w_in, cbuf);
  hipLaunchKernelGGL(k4_gemm, dim3(6400), dim3(256), 0, stream,
                     noise, wn_bf, cbuf, w_time, v_part);
  hipLaunchKernelGGL(k5_pred, dim3(4096), dim3(64), 0, stream, v_part, out);
}